// Round 6
// baseline (1330.949 us; speedup 1.0000x reference)
//
#include <hip/hip_runtime.h>
#include <hip/hip_bf16.h>
#include <stdint.h>

typedef unsigned short ushort_t;
typedef unsigned long long ull_t;
using bf16x8 = __attribute__((ext_vector_type(8))) short;
using f32x4  = __attribute__((ext_vector_type(4))) float;

#define SEQ    256
#define BATCH  64
#define INDIM  512
#define HDIM   1024
#define OUTDIM 256
#define MTOT   (SEQ*BATCH)   // 16384
#define BH     (BATCH*HDIM)

__device__ __forceinline__ ushort_t f2bf(float f) {
  uint32_t u = __builtin_bit_cast(uint32_t, f);
  u += 0x7fffu + ((u >> 16) & 1u);
  return (ushort_t)(u >> 16);
}
__device__ __forceinline__ float bf2f(ushort_t b) {
  uint32_t u = ((uint32_t)b) << 16;
  return __builtin_bit_cast(float, u);
}
__device__ __forceinline__ f32x4 mfma16(bf16x8 a, bf16x8 b, f32x4 c) {
  return __builtin_amdgcn_mfma_f32_16x16x32_bf16(a, b, c, 0, 0, 0);
}
__device__ __forceinline__ void gload16(const void* g, void* l) {
  __builtin_amdgcn_global_load_lds(
      (const __attribute__((address_space(1))) unsigned int*)g,
      (__attribute__((address_space(3))) unsigned int*)l, 16, 0, 0);
}
__device__ __forceinline__ float tanhfast(float z) {
  float e = __expf(2.0f * z);
  return 1.0f - 2.0f / (e + 1.0f);
}
__device__ __forceinline__ ull_t pack4bf(const float* v) {
  ull_t p = 0;
#pragma unroll
  for (int j = 0; j < 4; ++j) p |= (ull_t)f2bf(v[j]) << (16 * j);
  return p;
}
// L1-bypassing L2 read (fast-path flag poll). waitcnt fused in asm (rule #18).
__device__ __forceinline__ int load_sc0_int(const int* p) {
  int v;
  asm volatile("global_load_dword %0, %1, off sc0\n\ts_waitcnt vmcnt(0)"
               : "=&v"(v) : "v"(p) : "memory");
  return v;
}

// ---------------- prep kernels ----------------
__global__ void k_convert(const float* __restrict__ src, ushort_t* __restrict__ dst, int n) {
  int i = blockIdx.x * blockDim.x + threadIdx.x;
  if (i < n) dst[i] = f2bf(src[i]);
}
__global__ void k_split(const float* __restrict__ src, ushort_t* __restrict__ hi,
                        ushort_t* __restrict__ lo, int n) {
  int i = blockIdx.x * blockDim.x + threadIdx.x;
  if (i < n) {
    float v = src[i];
    ushort_t h = f2bf(v);
    hi[i] = h;
    lo[i] = f2bf(v - bf2f(h));
  }
}
__global__ void k_split_wc(const float* __restrict__ Wc,
                           ushort_t* __restrict__ WiH, ushort_t* __restrict__ WiL,
                           ushort_t* __restrict__ WhH, ushort_t* __restrict__ WhL) {
  int i = blockIdx.x * blockDim.x + threadIdx.x;
  if (i < HDIM * HDIM) {
    int row = i >> 10, k = i & 1023;
    float vi = Wc[(size_t)row * (2 * HDIM) + k];
    float vh = Wc[(size_t)row * (2 * HDIM) + HDIM + k];
    ushort_t ih = f2bf(vi);
    WiH[i] = ih; WiL[i] = f2bf(vi - bf2f(ih));
    ushort_t hh = f2bf(vh);
    WhH[i] = hh; WhL[i] = f2bf(vh - bf2f(hh));
  }
}

// ---------------- generic NT GEMM (validated r1-r5) ----------------
template<int SPLITB, int RELU, int OUTBF>
__global__ __launch_bounds__(256) void gemm_nt(
    const ushort_t* __restrict__ A, const ushort_t* __restrict__ Bhi,
    const ushort_t* __restrict__ Blo, const float* __restrict__ bias,
    float* __restrict__ Cf, ushort_t* __restrict__ Cb,
    int M, int N, int K)
{
  __shared__ ushort_t As[128 * 32];
  __shared__ ushort_t Bh[128 * 32];
  __shared__ ushort_t Bl[128 * 32];
  const int tid = threadIdx.x;
  const int w = tid >> 6, l = tid & 63;
  const int m0 = blockIdx.x * 128, n0 = blockIdx.y * 128;
  const int wr = w >> 1, wc = w & 1;
  const int lr = l & 15, lk = l >> 4;

  f32x4 acc[4][4] = {};
  const int nK = K >> 5;
  const size_t rowB = (size_t)K * 2;

  for (int kk = 0; kk < nK; ++kk) {
    const size_t kbyte = (size_t)kk * 64;
#pragma unroll
    for (int j = 0; j < 2; ++j) {
      int c = (w * 2 + j) * 64 + l;
      int row = c >> 2;
      int kb = (c & 3) * 16;
      gload16((const char*)A + (size_t)(m0 + row) * rowB + kbyte + kb,
              (char*)As + (w * 2 + j) * 1024);
      gload16((const char*)Bhi + (size_t)(n0 + row) * rowB + kbyte + kb,
              (char*)Bh + (w * 2 + j) * 1024);
      if (SPLITB)
        gload16((const char*)Blo + (size_t)(n0 + row) * rowB + kbyte + kb,
                (char*)Bl + (w * 2 + j) * 1024);
    }
    __syncthreads();
    bf16x8 af[4], bhf[4], blf[4];
#pragma unroll
    for (int i = 0; i < 4; ++i) {
      af[i]  = *(const bf16x8*)&As[(wr * 64 + i * 16 + lr) * 32 + lk * 8];
      bhf[i] = *(const bf16x8*)&Bh[(wc * 64 + i * 16 + lr) * 32 + lk * 8];
      if (SPLITB)
        blf[i] = *(const bf16x8*)&Bl[(wc * 64 + i * 16 + lr) * 32 + lk * 8];
    }
#pragma unroll
    for (int i = 0; i < 4; ++i)
#pragma unroll
      for (int j2 = 0; j2 < 4; ++j2) {
        acc[i][j2] = mfma16(af[i], bhf[j2], acc[i][j2]);
        if (SPLITB) acc[i][j2] = mfma16(af[i], blf[j2], acc[i][j2]);
      }
    __syncthreads();
  }
#pragma unroll
  for (int j2 = 0; j2 < 4; ++j2) {
    int n = n0 + wc * 64 + j2 * 16 + lr;
    float bv = bias ? bias[n] : 0.0f;
#pragma unroll
    for (int i = 0; i < 4; ++i) {
#pragma unroll
      for (int r = 0; r < 4; ++r) {
        int m = m0 + wr * 64 + i * 16 + lk * 4 + r;
        float v = acc[i][j2][r] + bv;
        if (RELU) v = fmaxf(v, 0.0f);
        if (OUTBF) Cb[(size_t)m * N + n] = f2bf(v);
        else       Cf[(size_t)m * N + n] = v;
      }
    }
  }
}

// ---------------- persistent scan kernel: XCD-local state AND flags ----------
// Grid 512 x 512 threads (8 waves), ~88KB LDS -> 1 block/CU; blocks on XCDs
// 0-3 claim one of 32 slots (over-provisioned -> groups always fill, no hang).
// amdgpu_waves_per_eu(2,2) pins 2 waves/EU -> 256-VGPR budget so the 128-VGPR
// weight slice stays register-resident (r5's VGPR=124 proved remat otherwise).
// State: plain write-through stores + vmcnt(0) into the XCD L2; first-touch
// plain loads (SEQ-deep archives -> L1 can never be stale). Flags: dual-path,
// flags_l2 (plain store / sc0 poll, fast) + flags_mall (agent atomics,
// r5-proven fallback polled every 4th round) -> hang-proof by construction.
// Iter i: A: h0(i)   = h0(i-1) + a0*tanh(P0[i] + Wh0*h0(i-1))        [i<SEQ]
//         B: h1(i-1) = h1(i-2) + a1*tanh(Wi*h0(i-1)+Wh1*h1(i-2)+b_c) [i>=1]
__global__ __attribute__((amdgpu_waves_per_eu(2, 2))) __launch_bounds__(512)
void scan_kernel(
    const float* __restrict__ P0,
    const ushort_t* __restrict__ WiH, const ushort_t* __restrict__ WiL,
    const ushort_t* __restrict__ WhH, const ushort_t* __restrict__ WhL,
    const float* __restrict__ b_c, const float* __restrict__ taus,
    ushort_t* __restrict__ h0buf,   // SEQ x 64x1024 bf16 (archive)
    ushort_t* __restrict__ H1buf,   // SEQ x 64x1024 bf16 (archive = h1 state)
    float* __restrict__ outHidden, int* __restrict__ sync)
{
  __shared__ float red[2][2][8][64][11];   // ~88KB -> 1 block/CU
  __shared__ int meta[2];

  const int tid = threadIdx.x;
  const int w = tid >> 6, l = tid & 63;
  const int lr = l & 15, lk = l >> 4;

  int* cnt        = sync;         // [8] per-XCD slot counters
  int* flags_l2   = sync + 64;    // [4][32] fast path (XCD L2)
  int* flags_mall = sync + 192;   // [4][32] fallback path (MALL)

  // ---- placement discovery ----
  if (tid == 0) {
    int xcd;
    asm volatile("s_getreg_b32 %0, hwreg(HW_REG_XCC_ID)" : "=s"(xcd));
    int slot = 999;
    if (xcd < 4)
      slot = __hip_atomic_fetch_add(&cnt[xcd], 1, __ATOMIC_RELAXED,
                                    __HIP_MEMORY_SCOPE_AGENT);
    meta[0] = (xcd < 4) ? xcd : -1;
    meta[1] = slot;
  }
  __syncthreads();
  const int g = meta[0];
  const int c = meta[1];
  if (g < 0 || c >= 32) return;   // surplus block: exit, frees the CU

  const int rowg = g * 16, colg = c * 32;
  const int kb = w * 128;

  // ---- one-time: weight slices into registers (2 ct x 4 frags x 4 mats = 128 VGPR)
  bf16x8 whh[2][4], whl[2][4], wih[2][4], wil[2][4];
#pragma unroll
  for (int ct = 0; ct < 2; ++ct)
#pragma unroll
    for (int kk = 0; kk < 4; ++kk) {
      size_t off = (size_t)(colg + ct * 16 + lr) * HDIM + kb + kk * 32 + lk * 8;
      whh[ct][kk] = *(const bf16x8*)&WhH[off];
      whl[ct][kk] = *(const bf16x8*)&WhL[off];
      wih[ct][kk] = *(const bf16x8*)&WiH[off];
      wil[ct][kk] = *(const bf16x8*)&WiL[off];
    }

  // epilogue mapping (waves 0,1; ct = w): lane -> row R, cols jc..jc+3
  const int R = l >> 2, jc = (l & 3) * 4;
  const int lo_base = 16 * (l >> 4);
  const int ro = (l >> 2) & 3;
  float hm0[4] = {0, 0, 0, 0}, hm1[4] = {0, 0, 0, 0};
  float bc4[4] = {0, 0, 0, 0};
  float a0c = 0.f, a1c = 0.f;
  float4 p0v = make_float4(0.f, 0.f, 0.f, 0.f);
  if (w < 2) {
#pragma unroll
    for (int j = 0; j < 4; ++j) bc4[j] = b_c[colg + w * 16 + jc + j];
    a0c = 0.05f / (taus[0] + 0.001f);
    a1c = 0.05f / (taus[1] + 0.001f);
    p0v = *(const float4*)&P0[((size_t)0 * BATCH + rowg + R) * HDIM + colg + w * 16 + jc];
  }

  for (int i = 0; i <= SEQ; ++i) {
    bf16x8 f[4], hh[4];
    f32x4 aA[2] = {}, aI[2] = {}, aH[2] = {};

    if (i >= 1) {
      const ushort_t* h0r = h0buf + (size_t)(i - 1) * BH;    // first touch
#pragma unroll
      for (int kk = 0; kk < 4; ++kk)
        f[kk] = *(const bf16x8*)&h0r[(size_t)(rowg + lr) * HDIM + kb + kk * 32 + lk * 8];
      if (i >= 2) {
        const ushort_t* h1r = H1buf + (size_t)(i - 2) * BH;  // first touch
#pragma unroll
        for (int kk = 0; kk < 4; ++kk)
          hh[kk] = *(const bf16x8*)&h1r[(size_t)(rowg + lr) * HDIM + kb + kk * 32 + lk * 8];
      }
#pragma unroll
      for (int kk = 0; kk < 4; ++kk)
#pragma unroll
        for (int ct = 0; ct < 2; ++ct) {
          aA[ct] = mfma16(f[kk], whh[ct][kk], aA[ct]);
          aA[ct] = mfma16(f[kk], whl[ct][kk], aA[ct]);
          aI[ct] = mfma16(f[kk], wih[ct][kk], aI[ct]);
          aI[ct] = mfma16(f[kk], wil[ct][kk], aI[ct]);
        }
      if (i >= 2) {
#pragma unroll
        for (int kk = 0; kk < 4; ++kk)
#pragma unroll
          for (int ct = 0; ct < 2; ++ct) {
            aH[ct] = mfma16(hh[kk], whh[ct][kk], aH[ct]);
            aH[ct] = mfma16(hh[kk], whl[ct][kk], aH[ct]);
          }
      }
    }
#pragma unroll
    for (int ct = 0; ct < 2; ++ct)
#pragma unroll
      for (int r = 0; r < 4; ++r) {
        red[0][ct][w][l][r] = aA[ct][r];
        red[1][ct][w][l][r] = aI[ct][r] + aH[ct][r];
      }
    __syncthreads();                                   // B1

    if (w < 2) {
      float sA[4], sB[4];
#pragma unroll
      for (int j = 0; j < 4; ++j) {
        const int src = jc + j + lo_base;
        float s0 = 0.f, s1 = 0.f;
#pragma unroll
        for (int q = 0; q < 8; ++q) {
          s0 += red[0][w][q][src][ro];
          s1 += red[1][w][q][src][ro];
        }
        sA[j] = s0; sB[j] = s1;
      }
      if (i < SEQ) {
        float p4[4] = {p0v.x, p0v.y, p0v.z, p0v.w};
#pragma unroll
        for (int j = 0; j < 4; ++j) hm0[j] += a0c * tanhfast(p4[j] + sA[j]);
        *(ull_t*)&h0buf[(size_t)i * BH + (size_t)(rowg + R) * HDIM +
                        colg + w * 16 + jc] = pack4bf(hm0);
      }
      if (i >= 1) {
#pragma unroll
        for (int j = 0; j < 4; ++j) hm1[j] += a1c * tanhfast(sB[j] + bc4[j]);
        *(ull_t*)&H1buf[(size_t)(i - 1) * BH + (size_t)(rowg + R) * HDIM +
                        colg + w * 16 + jc] = pack4bf(hm1);
      }
      asm volatile("s_waitcnt vmcnt(0)" ::: "memory"); // stores acked at L2
    }
    __syncthreads();                                   // B2

    if (i < SEQ) {
      if (tid == 0) {
        *(volatile int*)&flags_l2[g * 32 + c] = i + 1;   // write-through -> L2
        asm volatile("" ::: "memory");
        __hip_atomic_store(&flags_mall[g * 32 + c], i + 1, __ATOMIC_RELAXED,
                           __HIP_MEMORY_SCOPE_AGENT);    // MALL fallback
      }
      if (w < 2 && i + 1 < SEQ)
        p0v = *(const float4*)&P0[((size_t)(i + 1) * BATCH + rowg + R) * HDIM +
                                  colg + w * 16 + jc];
      if (w == 2) {
        const int target = i + 1;
        const int* fl2 = &flags_l2[g * 32 + (l & 31)];
        int* fml = &flags_mall[g * 32 + (l & 31)];
        for (int r = 0;; ++r) {
          int v = ((r & 3) == 3)
            ? __hip_atomic_load(fml, __ATOMIC_RELAXED, __HIP_MEMORY_SCOPE_AGENT)
            : load_sc0_int(fl2);
          if (__all(v >= target)) break;
        }
      }
      __syncthreads();                                 // B3
    }
  }

  if (w < 2) {
    float4 o0 = make_float4(hm0[0], hm0[1], hm0[2], hm0[3]);
    float4 o1 = make_float4(hm1[0], hm1[1], hm1[2], hm1[3]);
    *(float4*)&outHidden[(size_t)(rowg + R) * HDIM + colg + w * 16 + jc] = o0;
    *(float4*)&outHidden[(size_t)BH + (size_t)(rowg + R) * HDIM + colg + w * 16 + jc] = o1;
  }
}

// ---------------- host ----------------
extern "C" void kernel_launch(void* const* d_in, const int* in_sizes, int n_in,
                              void* d_out, int out_size, void* d_ws, size_t ws_size,
                              hipStream_t stream) {
  const float* x    = (const float*)d_in[0];
  const float* W_in = (const float*)d_in[1];
  const float* b_in = (const float*)d_in[2];
  const float* W_c  = (const float*)d_in[3];
  const float* b_c  = (const float*)d_in[4];
  const float* taus = (const float*)d_in[5];
  const float* W_o1 = (const float*)d_in[6];
  const float* b_o1 = (const float*)d_in[7];
  const float* W_o2 = (const float*)d_in[8];
  const float* b_o2 = (const float*)d_in[9];
  float* out = (float*)d_out;

  char* ws = (char*)d_ws;
  size_t off = 0;
  auto alloc = [&](size_t bytes) -> char* {
    char* p = ws + off;
    off += (bytes + 255) & ~(size_t)255;
    return p;
  };
  ushort_t* x_bf  = (ushort_t*)alloc((size_t)MTOT * INDIM * 2);     // 16 MB
  ushort_t* xp_b  = (ushort_t*)alloc((size_t)MTOT * HDIM * 2);      // 32 MB
  float*    P0    = (float*)   alloc((size_t)MTOT * HDIM * 4);      // 64 MB
  ushort_t* H1buf = (ushort_t*)alloc((size_t)MTOT * HDIM * 2);      // 32 MB
  ushort_t* h0buf = (ushort_t*)alloc((size_t)SEQ * BH * 2);         // 32 MB
  ushort_t* O1    = (ushort_t*)alloc((size_t)MTOT * (HDIM/2) * 2);  // 16 MB
  ushort_t* WiH   = (ushort_t*)alloc((size_t)HDIM * HDIM * 2);
  ushort_t* WiL   = (ushort_t*)alloc((size_t)HDIM * HDIM * 2);
  ushort_t* WhH   = (ushort_t*)alloc((size_t)HDIM * HDIM * 2);
  ushort_t* WhL   = (ushort_t*)alloc((size_t)HDIM * HDIM * 2);
  ushort_t* WinH  = (ushort_t*)alloc((size_t)HDIM * INDIM * 2);
  ushort_t* WinL  = (ushort_t*)alloc((size_t)HDIM * INDIM * 2);
  ushort_t* Wo1b  = (ushort_t*)alloc((size_t)(HDIM/2) * HDIM * 2);
  ushort_t* Wo2b  = (ushort_t*)alloc((size_t)OUTDIM * (HDIM/2) * 2);
  int*      sync  = (int*)     alloc(4096);
  if (off > ws_size) return;

  hipMemsetAsync(sync, 0, 4096, stream);

  k_convert<<<(MTOT * INDIM + 255) / 256, 256, 0, stream>>>(x, x_bf, MTOT * INDIM);
  k_split<<<(HDIM * INDIM + 255) / 256, 256, 0, stream>>>(W_in, WinH, WinL, HDIM * INDIM);
  k_split_wc<<<(HDIM * HDIM + 255) / 256, 256, 0, stream>>>(W_c, WiH, WiL, WhH, WhL);
  k_convert<<<((HDIM/2) * HDIM + 255) / 256, 256, 0, stream>>>(W_o1, Wo1b, (HDIM/2) * HDIM);
  k_convert<<<(OUTDIM * (HDIM/2) + 255) / 256, 256, 0, stream>>>(W_o2, Wo2b, OUTDIM * (HDIM/2));

  // xp = x @ W_in^T + b_in   -> bf16
  gemm_nt<1, 0, 1><<<dim3(MTOT / 128, HDIM / 128), 256, 0, stream>>>(
      x_bf, WinH, WinL, b_in, nullptr, xp_b, MTOT, HDIM, INDIM);
  // P0 = xp @ Wi^T + b_c     -> fp32
  gemm_nt<1, 0, 0><<<dim3(MTOT / 128, HDIM / 128), 256, 0, stream>>>(
      xp_b, WiH, WiL, b_c, P0, nullptr, MTOT, HDIM, HDIM);

  // sequential scan: 4 XCD-local groups x 32 worker blocks (over-provisioned)
  scan_kernel<<<512, 512, 0, stream>>>(P0, WiH, WiL, WhH, WhL, b_c, taus,
                                       h0buf, H1buf,
                                       out + (size_t)SEQ * BATCH * OUTDIM, sync);

  // O1 = relu(H1 @ W_o1^T + b_o1) -> bf16
  gemm_nt<0, 1, 1><<<dim3(MTOT / 128, (HDIM/2) / 128), 256, 0, stream>>>(
      H1buf, Wo1b, nullptr, b_o1, nullptr, O1, MTOT, HDIM / 2, HDIM);
  // out = O1 @ W_o2^T + b_o2 -> fp32
  gemm_nt<0, 0, 0><<<dim3(MTOT / 128, OUTDIM / 128), 256, 0, stream>>>(
      O1, Wo2b, nullptr, b_o2, out, nullptr, MTOT, OUTDIM, HDIM / 2);
}

// Round 7
// 1227.291 us; speedup vs baseline: 1.0845x; 1.0845x over previous
//
#include <hip/hip_runtime.h>
#include <hip/hip_bf16.h>
#include <stdint.h>

typedef unsigned short ushort_t;
typedef unsigned long long ull_t;
using bf16x8 = __attribute__((ext_vector_type(8))) short;
using f32x4  = __attribute__((ext_vector_type(4))) float;

#define SEQ    256
#define BATCH  64
#define INDIM  512
#define HDIM   1024
#define OUTDIM 256
#define MTOT   (SEQ*BATCH)   // 16384
#define BH     (BATCH*HDIM)

__device__ __forceinline__ ushort_t f2bf(float f) {
  uint32_t u = __builtin_bit_cast(uint32_t, f);
  u += 0x7fffu + ((u >> 16) & 1u);
  return (ushort_t)(u >> 16);
}
__device__ __forceinline__ float bf2f(ushort_t b) {
  uint32_t u = ((uint32_t)b) << 16;
  return __builtin_bit_cast(float, u);
}
__device__ __forceinline__ f32x4 mfma16(bf16x8 a, bf16x8 b, f32x4 c) {
  return __builtin_amdgcn_mfma_f32_16x16x32_bf16(a, b, c, 0, 0, 0);
}
__device__ __forceinline__ void gload16(const void* g, void* l) {
  __builtin_amdgcn_global_load_lds(
      (const __attribute__((address_space(1))) unsigned int*)g,
      (__attribute__((address_space(3))) unsigned int*)l, 16, 0, 0);
}
__device__ __forceinline__ float tanhfast(float z) {
  float e = __expf(2.0f * z);
  return 1.0f - 2.0f / (e + 1.0f);
}
// L1-bypassing L2 read (fast-path flag poll). waitcnt fused in asm (rule #18).
__device__ __forceinline__ int load_sc0_int(const int* p) {
  int v;
  asm volatile("global_load_dword %0, %1, off sc0\n\ts_waitcnt vmcnt(0)"
               : "=&v"(v) : "v"(p) : "memory");
  return v;
}

// ---------------- prep kernels ----------------
__global__ void k_convert(const float* __restrict__ src, ushort_t* __restrict__ dst, int n) {
  int i = blockIdx.x * blockDim.x + threadIdx.x;
  if (i < n) dst[i] = f2bf(src[i]);
}
__global__ void k_split(const float* __restrict__ src, ushort_t* __restrict__ hi,
                        ushort_t* __restrict__ lo, int n) {
  int i = blockIdx.x * blockDim.x + threadIdx.x;
  if (i < n) {
    float v = src[i];
    ushort_t h = f2bf(v);
    hi[i] = h;
    lo[i] = f2bf(v - bf2f(h));
  }
}
__global__ void k_split_wc(const float* __restrict__ Wc,
                           ushort_t* __restrict__ WiH, ushort_t* __restrict__ WiL,
                           ushort_t* __restrict__ WhH, ushort_t* __restrict__ WhL) {
  int i = blockIdx.x * blockDim.x + threadIdx.x;
  if (i < HDIM * HDIM) {
    int row = i >> 10, k = i & 1023;
    float vi = Wc[(size_t)row * (2 * HDIM) + k];
    float vh = Wc[(size_t)row * (2 * HDIM) + HDIM + k];
    ushort_t ih = f2bf(vi);
    WiH[i] = ih; WiL[i] = f2bf(vi - bf2f(ih));
    ushort_t hh = f2bf(vh);
    WhH[i] = hh; WhL[i] = f2bf(vh - bf2f(hh));
  }
}

// ---------------- generic NT GEMM (validated r1-r6) ----------------
template<int SPLITB, int RELU, int OUTBF>
__global__ __launch_bounds__(256) void gemm_nt(
    const ushort_t* __restrict__ A, const ushort_t* __restrict__ Bhi,
    const ushort_t* __restrict__ Blo, const float* __restrict__ bias,
    float* __restrict__ Cf, ushort_t* __restrict__ Cb,
    int M, int N, int K)
{
  __shared__ ushort_t As[128 * 32];
  __shared__ ushort_t Bh[128 * 32];
  __shared__ ushort_t Bl[128 * 32];
  const int tid = threadIdx.x;
  const int w = tid >> 6, l = tid & 63;
  const int m0 = blockIdx.x * 128, n0 = blockIdx.y * 128;
  const int wr = w >> 1, wc = w & 1;
  const int lr = l & 15, lk = l >> 4;

  f32x4 acc[4][4] = {};
  const int nK = K >> 5;
  const size_t rowB = (size_t)K * 2;

  for (int kk = 0; kk < nK; ++kk) {
    const size_t kbyte = (size_t)kk * 64;
#pragma unroll
    for (int j = 0; j < 2; ++j) {
      int c = (w * 2 + j) * 64 + l;
      int row = c >> 2;
      int kb = (c & 3) * 16;
      gload16((const char*)A + (size_t)(m0 + row) * rowB + kbyte + kb,
              (char*)As + (w * 2 + j) * 1024);
      gload16((const char*)Bhi + (size_t)(n0 + row) * rowB + kbyte + kb,
              (char*)Bh + (w * 2 + j) * 1024);
      if (SPLITB)
        gload16((const char*)Blo + (size_t)(n0 + row) * rowB + kbyte + kb,
                (char*)Bl + (w * 2 + j) * 1024);
    }
    __syncthreads();
    bf16x8 af[4], bhf[4], blf[4];
#pragma unroll
    for (int i = 0; i < 4; ++i) {
      af[i]  = *(const bf16x8*)&As[(wr * 64 + i * 16 + lr) * 32 + lk * 8];
      bhf[i] = *(const bf16x8*)&Bh[(wc * 64 + i * 16 + lr) * 32 + lk * 8];
      if (SPLITB)
        blf[i] = *(const bf16x8*)&Bl[(wc * 64 + i * 16 + lr) * 32 + lk * 8];
    }
#pragma unroll
    for (int i = 0; i < 4; ++i)
#pragma unroll
      for (int j2 = 0; j2 < 4; ++j2) {
        acc[i][j2] = mfma16(af[i], bhf[j2], acc[i][j2]);
        if (SPLITB) acc[i][j2] = mfma16(af[i], blf[j2], acc[i][j2]);
      }
    __syncthreads();
  }
#pragma unroll
  for (int j2 = 0; j2 < 4; ++j2) {
    int n = n0 + wc * 64 + j2 * 16 + lr;
    float bv = bias ? bias[n] : 0.0f;
#pragma unroll
    for (int i = 0; i < 4; ++i) {
#pragma unroll
      for (int r = 0; r < 4; ++r) {
        int m = m0 + wr * 64 + i * 16 + lk * 4 + r;
        float v = acc[i][j2][r] + bv;
        if (RELU) v = fmaxf(v, 0.0f);
        if (OUTBF) Cb[(size_t)m * N + n] = f2bf(v);
        else       Cf[(size_t)m * N + n] = v;
      }
    }
  }
}

// ---------------- persistent scan kernel: 16 waves, register-resident weights
// 512 blocks x 1024 threads (16 waves). launch_bounds(1024,4) -> hard 128-VGPR
// cap; per-lane weight slice is 64 VGPR (16 x bf16x8) so the WHOLE live set
// fits -> no per-iteration weight reloads (r5/r6's hidden cost: VGPR=124 <
// needed 128+ proved remat). K-slice 64/wave. Workers: XCDs 0-3, 32 slots
// (claim via XCC_ID + atomic, over-provisioned grid -> hang-proof). State via
// XCD L2 (plain write-through stores + vmcnt ack; first-touch plain loads on
// SEQ-deep archives -> no stale L1). Flags dual-path (L2 sc0 + MALL fallback).
// Iter i: A: h0(i)   = h0(i-1) + a0*tanh(P0[i] + Wh*h0(i-1))         [i<SEQ]
//         B: h1(i-1) = h1(i-2) + a1*tanh(Wi*h0(i-1)+Wh*h1(i-2)+b_c)  [i>=1]
__global__ __launch_bounds__(1024, 4) void scan_kernel(
    const float* __restrict__ P0,
    const ushort_t* __restrict__ WiH, const ushort_t* __restrict__ WiL,
    const ushort_t* __restrict__ WhH, const ushort_t* __restrict__ WhL,
    const float* __restrict__ b_c, const float* __restrict__ taus,
    ushort_t* __restrict__ h0buf,   // SEQ x 64x1024 bf16 (archive)
    ushort_t* __restrict__ H1buf,   // SEQ x 64x1024 bf16 (archive = h1 state)
    float* __restrict__ outHidden, int* __restrict__ sync)
{
  __shared__ float red[4 * 16 * 320];   // [tile(ph,ct)][q=wave][col*20+row] = 80KB
  __shared__ int meta[2];

  const int tid = threadIdx.x;
  const int w = tid >> 6, l = tid & 63;
  const int lr = l & 15, lk = l >> 4;

  int* cnt        = sync;         // [8] per-XCD slot counters
  int* flags_l2   = sync + 64;    // [4][32] fast path (XCD L2)
  int* flags_mall = sync + 192;   // [4][32] fallback path (MALL)

  // ---- placement discovery ----
  if (tid == 0) {
    int xcd;
    asm volatile("s_getreg_b32 %0, hwreg(HW_REG_XCC_ID)" : "=s"(xcd));
    int slot = 999;
    if (xcd < 4)
      slot = __hip_atomic_fetch_add(&cnt[xcd], 1, __ATOMIC_RELAXED,
                                    __HIP_MEMORY_SCOPE_AGENT);
    meta[0] = (xcd < 4) ? xcd : -1;
    meta[1] = slot;
  }
  __syncthreads();
  const int g = meta[0];
  const int c = meta[1];
  if (g < 0 || c >= 32) return;   // surplus block: exit, frees the CU

  const int rowg = g * 16, colg = c * 32;
  const int kb = w * 64;          // K-slice 64 per wave

  // ---- one-time: weight slices (2 ct x 2 kk x 4 mats = 16 bf16x8 = 64 VGPR)
  bf16x8 whh[2][2], whl[2][2], wih[2][2], wil[2][2];
#pragma unroll
  for (int ct = 0; ct < 2; ++ct)
#pragma unroll
    for (int kk = 0; kk < 2; ++kk) {
      size_t off = (size_t)(colg + ct * 16 + lr) * HDIM + kb + kk * 32 + lk * 8;
      whh[ct][kk] = *(const bf16x8*)&WhH[off];
      whl[ct][kk] = *(const bf16x8*)&WhL[off];
      wih[ct][kk] = *(const bf16x8*)&WiH[off];
      wil[ct][kk] = *(const bf16x8*)&WiL[off];
    }

  // epilogue mapping (waves 0-3): tile = w = ph*2+ct; lane owns col ec, rows R0..R0+3
  const int ep = (w < 4);
  const int ph = w >> 1, ect = w & 1;
  const int ec = lr, R0 = lk * 4;
  float hm[4] = {0, 0, 0, 0};
  float bcn = 0.f, alpha = 0.f;
  float p0r[4] = {0, 0, 0, 0};
  if (ep) {
    alpha = 0.05f / (taus[ph] + 0.001f);
    bcn = b_c[colg + ect * 16 + ec];
    if (ph == 0) {
#pragma unroll
      for (int j = 0; j < 4; ++j)
        p0r[j] = P0[((size_t)0 * BATCH + rowg + R0 + j) * HDIM + colg + ect * 16 + ec];
    }
  }

  for (int i = 0; i <= SEQ; ++i) {
    // pin weights live across the backedge (defeat remat/spill of the slice)
#pragma unroll
    for (int ct = 0; ct < 2; ++ct)
#pragma unroll
      for (int kk = 0; kk < 2; ++kk)
        asm volatile("" : "+v"(whh[ct][kk]), "+v"(whl[ct][kk]),
                          "+v"(wih[ct][kk]), "+v"(wil[ct][kk]));

    bf16x8 f0 = {}, f1 = {}, g0 = {}, g1 = {};
    f32x4 aA[2] = {}, aI[2] = {}, aH[2] = {};
    if (i >= 1) {
      const ushort_t* h0r = h0buf + (size_t)(i - 1) * BH;   // first touch
      f0 = *(const bf16x8*)&h0r[(size_t)(rowg + lr) * HDIM + kb + lk * 8];
      f1 = *(const bf16x8*)&h0r[(size_t)(rowg + lr) * HDIM + kb + 32 + lk * 8];
      if (i >= 2) {
        const ushort_t* h1r = H1buf + (size_t)(i - 2) * BH; // first touch
        g0 = *(const bf16x8*)&h1r[(size_t)(rowg + lr) * HDIM + kb + lk * 8];
        g1 = *(const bf16x8*)&h1r[(size_t)(rowg + lr) * HDIM + kb + 32 + lk * 8];
      }
#pragma unroll
      for (int ct = 0; ct < 2; ++ct) {
        aA[ct] = mfma16(f0, whh[ct][0], aA[ct]);
        aA[ct] = mfma16(f0, whl[ct][0], aA[ct]);
        aA[ct] = mfma16(f1, whh[ct][1], aA[ct]);
        aA[ct] = mfma16(f1, whl[ct][1], aA[ct]);
        aI[ct] = mfma16(f0, wih[ct][0], aI[ct]);
        aI[ct] = mfma16(f0, wil[ct][0], aI[ct]);
        aI[ct] = mfma16(f1, wih[ct][1], aI[ct]);
        aI[ct] = mfma16(f1, wil[ct][1], aI[ct]);
      }
      if (i >= 2) {
#pragma unroll
        for (int ct = 0; ct < 2; ++ct) {
          aH[ct] = mfma16(g0, whh[ct][0], aH[ct]);
          aH[ct] = mfma16(g0, whl[ct][0], aH[ct]);
          aH[ct] = mfma16(g1, whh[ct][1], aH[ct]);
          aH[ct] = mfma16(g1, whl[ct][1], aH[ct]);
        }
      }
    }
    // write partials: D-layout col=l&15, row=lk*4+r -> red[col*20+row] (b128)
    const int wbase = lr * 20 + lk * 4;
#pragma unroll
    for (int ct = 0; ct < 2; ++ct) {
      *(f32x4*)&red[((0 + ct) * 16 + w) * 320 + wbase] = aA[ct];
      f32x4 pb = aI[ct] + aH[ct];
      *(f32x4*)&red[((2 + ct) * 16 + w) * 320 + wbase] = pb;
    }
    __syncthreads();                                   // B1

    if (ep && ((ph == 0 && i < SEQ) || (ph == 1 && i >= 1))) {
      f32x4 s = {};
      const float* rb = &red[(w * 16) * 320 + ec * 20 + R0];
#pragma unroll
      for (int q = 0; q < 16; ++q)
        s += *(const f32x4*)&rb[q * 320];
      if (ph == 0) {
        ushort_t* dst = &h0buf[(size_t)i * BH + (size_t)(rowg + R0) * HDIM +
                               colg + ect * 16 + ec];
#pragma unroll
        for (int j = 0; j < 4; ++j) {
          hm[j] += alpha * tanhfast(p0r[j] + s[j]);
          dst[(size_t)j * HDIM] = f2bf(hm[j]);
        }
      } else {
        ushort_t* dst = &H1buf[(size_t)(i - 1) * BH + (size_t)(rowg + R0) * HDIM +
                               colg + ect * 16 + ec];
#pragma unroll
        for (int j = 0; j < 4; ++j) {
          hm[j] += alpha * tanhfast(s[j] + bcn);
          dst[(size_t)j * HDIM] = f2bf(hm[j]);
        }
      }
      asm volatile("s_waitcnt vmcnt(0)" ::: "memory"); // stores acked at L2
    }
    __syncthreads();                                   // B2

    if (i < SEQ) {
      if (tid == 0) {
        *(volatile int*)&flags_l2[g * 32 + c] = i + 1;   // write-through -> L2
        asm volatile("" ::: "memory");
        __hip_atomic_store(&flags_mall[g * 32 + c], i + 1, __ATOMIC_RELAXED,
                           __HIP_MEMORY_SCOPE_AGENT);    // MALL fallback
      }
      if (ep && ph == 0 && i + 1 < SEQ) {
#pragma unroll
        for (int j = 0; j < 4; ++j)
          p0r[j] = P0[((size_t)(i + 1) * BATCH + rowg + R0 + j) * HDIM +
                      colg + ect * 16 + ec];
      }
      if (w == 4) {
        const int target = i + 1;
        const int* fl2 = &flags_l2[g * 32 + (l & 31)];
        int* fml = &flags_mall[g * 32 + (l & 31)];
        for (int r = 0;; ++r) {
          int v = ((r & 3) == 3)
            ? __hip_atomic_load(fml, __ATOMIC_RELAXED, __HIP_MEMORY_SCOPE_AGENT)
            : load_sc0_int(fl2);
          if (__all(v >= target)) break;
        }
      }
      __syncthreads();                                 // B3
    }
  }

  // hidden_final [2][64][1024]: layer = ph
  if (ep) {
    float* dst = &outHidden[(size_t)ph * BH + (size_t)(rowg + R0) * HDIM +
                            colg + ect * 16 + ec];
#pragma unroll
    for (int j = 0; j < 4; ++j) dst[(size_t)j * HDIM] = hm[j];
  }
}

// ---------------- host ----------------
extern "C" void kernel_launch(void* const* d_in, const int* in_sizes, int n_in,
                              void* d_out, int out_size, void* d_ws, size_t ws_size,
                              hipStream_t stream) {
  const float* x    = (const float*)d_in[0];
  const float* W_in = (const float*)d_in[1];
  const float* b_in = (const float*)d_in[2];
  const float* W_c  = (const float*)d_in[3];
  const float* b_c  = (const float*)d_in[4];
  const float* taus = (const float*)d_in[5];
  const float* W_o1 = (const float*)d_in[6];
  const float* b_o1 = (const float*)d_in[7];
  const float* W_o2 = (const float*)d_in[8];
  const float* b_o2 = (const float*)d_in[9];
  float* out = (float*)d_out;

  char* ws = (char*)d_ws;
  size_t off = 0;
  auto alloc = [&](size_t bytes) -> char* {
    char* p = ws + off;
    off += (bytes + 255) & ~(size_t)255;
    return p;
  };
  ushort_t* x_bf  = (ushort_t*)alloc((size_t)MTOT * INDIM * 2);     // 16 MB
  ushort_t* xp_b  = (ushort_t*)alloc((size_t)MTOT * HDIM * 2);      // 32 MB
  float*    P0    = (float*)   alloc((size_t)MTOT * HDIM * 4);      // 64 MB
  ushort_t* H1buf = (ushort_t*)alloc((size_t)MTOT * HDIM * 2);      // 32 MB
  ushort_t* h0buf = (ushort_t*)alloc((size_t)SEQ * BH * 2);         // 32 MB
  ushort_t* O1    = (ushort_t*)alloc((size_t)MTOT * (HDIM/2) * 2);  // 16 MB
  ushort_t* WiH   = (ushort_t*)alloc((size_t)HDIM * HDIM * 2);
  ushort_t* WiL   = (ushort_t*)alloc((size_t)HDIM * HDIM * 2);
  ushort_t* WhH   = (ushort_t*)alloc((size_t)HDIM * HDIM * 2);
  ushort_t* WhL   = (ushort_t*)alloc((size_t)HDIM * HDIM * 2);
  ushort_t* WinH  = (ushort_t*)alloc((size_t)HDIM * INDIM * 2);
  ushort_t* WinL  = (ushort_t*)alloc((size_t)HDIM * INDIM * 2);
  ushort_t* Wo1b  = (ushort_t*)alloc((size_t)(HDIM/2) * HDIM * 2);
  ushort_t* Wo2b  = (ushort_t*)alloc((size_t)OUTDIM * (HDIM/2) * 2);
  int*      sync  = (int*)     alloc(4096);
  if (off > ws_size) return;

  hipMemsetAsync(sync, 0, 4096, stream);

  k_convert<<<(MTOT * INDIM + 255) / 256, 256, 0, stream>>>(x, x_bf, MTOT * INDIM);
  k_split<<<(HDIM * INDIM + 255) / 256, 256, 0, stream>>>(W_in, WinH, WinL, HDIM * INDIM);
  k_split_wc<<<(HDIM * HDIM + 255) / 256, 256, 0, stream>>>(W_c, WiH, WiL, WhH, WhL);
  k_convert<<<((HDIM/2) * HDIM + 255) / 256, 256, 0, stream>>>(W_o1, Wo1b, (HDIM/2) * HDIM);
  k_convert<<<(OUTDIM * (HDIM/2) + 255) / 256, 256, 0, stream>>>(W_o2, Wo2b, OUTDIM * (HDIM/2));

  // xp = x @ W_in^T + b_in   -> bf16
  gemm_nt<1, 0, 1><<<dim3(MTOT / 128, HDIM / 128), 256, 0, stream>>>(
      x_bf, WinH, WinL, b_in, nullptr, xp_b, MTOT, HDIM, INDIM);
  // P0 = xp @ Wi^T + b_c     -> fp32
  gemm_nt<1, 0, 0><<<dim3(MTOT / 128, HDIM / 128), 256, 0, stream>>>(
      xp_b, WiH, WiL, b_c, P0, nullptr, MTOT, HDIM, HDIM);

  // sequential scan: 4 XCD-local groups x 32 worker blocks x 16 waves
  scan_kernel<<<512, 1024, 0, stream>>>(P0, WiH, WiL, WhH, WhL, b_c, taus,
                                        h0buf, H1buf,
                                        out + (size_t)SEQ * BATCH * OUTDIM, sync);

  // O1 = relu(H1 @ W_o1^T + b_o1) -> bf16
  gemm_nt<0, 1, 1><<<dim3(MTOT / 128, (HDIM/2) / 128), 256, 0, stream>>>(
      H1buf, Wo1b, nullptr, b_o1, nullptr, O1, MTOT, HDIM / 2, HDIM);
  // out = O1 @ W_o2^T + b_o2 -> fp32
  gemm_nt<0, 0, 0><<<dim3(MTOT / 128, OUTDIM / 128), 256, 0, stream>>>(
      O1, Wo2b, nullptr, b_o2, out, nullptr, MTOT, OUTDIM, HDIM / 2);
}